// Round 1
// baseline (1582.620 us; speedup 1.0000x reference)
//
#include <hip/hip_runtime.h>
#include <math.h>

#define LDIM 4096   // L = 64*64
#define NC   256
#define W66  66
#define P66  4356   // 66*66
#define BZ   4
#define EPSK 1e-7f

// ---------------- rnorm: 1/||x[:,l]+eps|| per (b,l) ----------------
__global__ __launch_bounds__(256) void rnorm_kernel(const float* __restrict__ x,
                                                    float* __restrict__ rnorm) {
    int idx = blockIdx.x * 256 + threadIdx.x;      // over BZ*LDIM = 16384
    int b = idx >> 12;
    int l = idx & (LDIM - 1);
    const float* xb = x + (size_t)b * NC * LDIM + l;
    float s = 0.f;
#pragma unroll 8
    for (int c = 0; c < NC; ++c) {
        float v = xb[(size_t)c * LDIM] + EPSK;
        s += v * v;
    }
    rnorm[idx] = 1.0f / sqrtf(s);
}

// ---------------- Kcm[b][c][l] = (x+eps)*rnorm[b][l] ----------------
__global__ __launch_bounds__(256) void kcm_kernel(const float* __restrict__ x,
                                                  const float* __restrict__ rnorm,
                                                  float* __restrict__ kcm) {
    size_t idx = (size_t)blockIdx.x * 256 + threadIdx.x;  // over BZ*NC*LDIM
    int l = (int)(idx & (LDIM - 1));
    int b = (int)(idx >> 20);   // NC*LDIM = 2^20
    kcm[idx] = (x[idx] + EPSK) * rnorm[b * LDIM + l];
}

// ---------------- Pm[b][c][u*66+v] = 3x3 clipped sum of x core ----------------
__global__ __launch_bounds__(256) void pool_kernel(const float* __restrict__ x,
                                                   float* __restrict__ Pm) {
    size_t idx = (size_t)blockIdx.x * 256 + threadIdx.x;  // over BZ*NC*P66
    int p = (int)(idx % P66);
    size_t bc = idx / P66;
    int u = p / W66, v = p % W66;
    const float* xbc = x + bc * (size_t)LDIM;
    int i0 = max(u - 2, 0), i1 = min(u, 63);
    int j0 = max(v - 2, 0), j1 = min(v, 63);
    float s = 0.f;
    for (int i = i0; i <= i1; ++i)
        for (int j = j0; j <= j1; ++j)
            s += xbc[i * 64 + j];
    Pm[idx] = s;
}

// ---------------- GEMM1 (TN): C[p][l] = sum_c Pm[c][p]*Kcm[c][l] -> att ----------------
__global__ __launch_bounds__(256) void gemm1_kernel(const float* __restrict__ Pm,
                                                    const float* __restrict__ Kcm,
                                                    float* __restrict__ att) {
    __shared__ float As[16][64];  // [c][p]
    __shared__ float Bs[16][64];  // [c][l]
    int b  = blockIdx.z;
    int p0 = blockIdx.y * 64;
    int l0 = blockIdx.x * 64;
    const float* A = Pm  + (size_t)b * NC * P66;
    const float* B = Kcm + (size_t)b * NC * LDIM;
    float* C = att + (size_t)b * P66 * LDIM;

    int tid = threadIdx.x;
    int tx = tid & 15, ty = tid >> 4;
    int lc = tid & 63;   // column within tile
    int lr = tid >> 6;   // 0..3
    float acc[4][4] = {};

    for (int c0 = 0; c0 < NC; c0 += 16) {
#pragma unroll
        for (int r = 0; r < 4; ++r) {
            int c = c0 + lr + r * 4;
            int p = p0 + lc;
            As[lr + r * 4][lc] = (p < P66) ? A[(size_t)c * P66 + p] : 0.f;
            Bs[lr + r * 4][lc] = B[(size_t)c * LDIM + l0 + lc];
        }
        __syncthreads();
#pragma unroll
        for (int kk = 0; kk < 16; ++kk) {
            float a0[4], b0[4];
#pragma unroll
            for (int i = 0; i < 4; ++i) a0[i] = As[kk][ty * 4 + i];
#pragma unroll
            for (int j = 0; j < 4; ++j) b0[j] = Bs[kk][tx * 4 + j];
#pragma unroll
            for (int i = 0; i < 4; ++i)
#pragma unroll
                for (int j = 0; j < 4; ++j) acc[i][j] += a0[i] * b0[j];
        }
        __syncthreads();
    }
#pragma unroll
    for (int i = 0; i < 4; ++i) {
        int p = p0 + ty * 4 + i;
        if (p < P66) {
            float4 v = make_float4(acc[i][0], acc[i][1], acc[i][2], acc[i][3]);
            *(float4*)(C + (size_t)p * LDIM + l0 + tx * 4) = v;
        }
    }
}

// ---------------- softmax over l, in place on att rows ----------------
__global__ __launch_bounds__(256) void softmax_kernel(float* __restrict__ att) {
    float* row = att + (size_t)blockIdx.x * LDIM;
    int tid = threadIdx.x;
    float4 v[4];
    float mx = -1e30f;
#pragma unroll
    for (int i = 0; i < 4; ++i) {
        v[i] = ((float4*)row)[tid + i * 256];
        mx = fmaxf(mx, fmaxf(fmaxf(v[i].x, v[i].y), fmaxf(v[i].z, v[i].w)));
    }
    __shared__ float sred[4];
    __shared__ float ssum[4];
#pragma unroll
    for (int off = 32; off > 0; off >>= 1) mx = fmaxf(mx, __shfl_xor(mx, off));
    if ((tid & 63) == 0) sred[tid >> 6] = mx;
    __syncthreads();
    float m4 = fmaxf(fmaxf(sred[0], sred[1]), fmaxf(sred[2], sred[3]));
    float sum = 0.f;
#pragma unroll
    for (int i = 0; i < 4; ++i) {
        v[i].x = __expf(v[i].x - m4);
        v[i].y = __expf(v[i].y - m4);
        v[i].z = __expf(v[i].z - m4);
        v[i].w = __expf(v[i].w - m4);
        sum += (v[i].x + v[i].y) + (v[i].z + v[i].w);
    }
#pragma unroll
    for (int off = 32; off > 0; off >>= 1) sum += __shfl_xor(sum, off);
    if ((tid & 63) == 0) ssum[tid >> 6] = sum;
    __syncthreads();
    float r = 1.0f / (ssum[0] + ssum[1] + ssum[2] + ssum[3]);
#pragma unroll
    for (int i = 0; i < 4; ++i) {
        v[i].x *= r; v[i].y *= r; v[i].z *= r; v[i].w *= r;
        ((float4*)row)[tid + i * 256] = v[i];
    }
}

// ---------------- GEMM2 (NT): out[c][i] = sum_l Kcm[c][l]*att[p(i)][l] ----------------
__global__ __launch_bounds__(256) void gemm2_kernel(const float* __restrict__ Kcm,
                                                    const float* __restrict__ att,
                                                    float* __restrict__ outp) {
    __shared__ float Ks[16][65];  // [kk][c]
    __shared__ float Qs[16][65];  // [kk][i]
    int b  = blockIdx.z;
    int c0 = blockIdx.y * 64;
    int i0 = blockIdx.x * 64;
    const float* A    = Kcm + (size_t)b * NC * LDIM;
    const float* Batt = att + (size_t)b * P66 * LDIM;
    int tid = threadIdx.x;
    int tx = tid & 15, ty = tid >> 4;
    int lrow = tid >> 2;        // 0..63
    int lcol = (tid & 3) * 4;   // 0,4,8,12
    int i = i0 + lrow;
    int p = (i / 64 + 1) * W66 + (i % 64 + 1);
    const float* Arow = A    + (size_t)(c0 + lrow) * LDIM;
    const float* Brow = Batt + (size_t)p * LDIM;
    float acc[4][4] = {};

    for (int l0 = 0; l0 < LDIM; l0 += 16) {
        float4 av = *(const float4*)(Arow + l0 + lcol);
        float4 bv = *(const float4*)(Brow + l0 + lcol);
        Ks[lcol + 0][lrow] = av.x; Ks[lcol + 1][lrow] = av.y;
        Ks[lcol + 2][lrow] = av.z; Ks[lcol + 3][lrow] = av.w;
        Qs[lcol + 0][lrow] = bv.x; Qs[lcol + 1][lrow] = bv.y;
        Qs[lcol + 2][lrow] = bv.z; Qs[lcol + 3][lrow] = bv.w;
        __syncthreads();
#pragma unroll
        for (int kk = 0; kk < 16; ++kk) {
            float a0[4], b0[4];
#pragma unroll
            for (int ii = 0; ii < 4; ++ii) a0[ii] = Ks[kk][ty * 4 + ii];
#pragma unroll
            for (int jj = 0; jj < 4; ++jj) b0[jj] = Qs[kk][tx * 4 + jj];
#pragma unroll
            for (int ii = 0; ii < 4; ++ii)
#pragma unroll
                for (int jj = 0; jj < 4; ++jj) acc[ii][jj] += a0[ii] * b0[jj];
        }
        __syncthreads();
    }
#pragma unroll
    for (int r = 0; r < 4; ++r) {
        float4 v = make_float4(acc[r][0], acc[r][1], acc[r][2], acc[r][3]);
        *(float4*)(outp + ((size_t)(b * NC + c0 + ty * 4 + r)) * LDIM + i0 + tx * 4) = v;
    }
}

extern "C" void kernel_launch(void* const* d_in, const int* in_sizes, int n_in,
                              void* d_out, int out_size, void* d_ws, size_t ws_size,
                              hipStream_t stream) {
    const float* x = (const float*)d_in[0];       // [4,256,64,64]
    float* out = (float*)d_out;                   // [4,256,64,64] = 4194304 floats
    float* att = (float*)d_out + 4194304;         // [4][4356][4096] position-major
    float* rnorm = (float*)d_ws;                  // 16384 floats
    float* Kcm   = rnorm + 16384;                 // 4*256*4096 floats
    float* Pm    = Kcm + 4194304;                 // 4*256*4356 floats

    rnorm_kernel<<<64, 256, 0, stream>>>(x, rnorm);
    kcm_kernel<<<16384, 256, 0, stream>>>(x, rnorm, Kcm);
    pool_kernel<<<17424, 256, 0, stream>>>(x, Pm);
    dim3 g1(64, 69, BZ);
    gemm1_kernel<<<g1, 256, 0, stream>>>(Pm, Kcm, att);
    softmax_kernel<<<17424, 256, 0, stream>>>(att);
    dim3 g2(64, 4, BZ);
    gemm2_kernel<<<g2, 256, 0, stream>>>(Kcm, att, out);
}

// Round 2
// 677.405 us; speedup vs baseline: 2.3363x; 2.3363x over previous
//
#include <hip/hip_runtime.h>
#include <math.h>
#include <stdint.h>

#define LDIM 4096   // L = 64*64
#define NC   256
#define W66  66
#define P66  4356   // 66*66
#define BZ   4
#define EPSK 1e-7f

typedef _Float16 v8h __attribute__((ext_vector_type(8)));
typedef float v4f __attribute__((ext_vector_type(4)));

__device__ __forceinline__ void cp16(const void* g, void* l) {
    __builtin_amdgcn_global_load_lds(
        (const __attribute__((address_space(1))) void*)g,
        (__attribute__((address_space(3))) void*)l, 16, 0, 0);
}

// ---------------- rnorm: 1/||x[:,l]+eps|| per (b,l) ----------------
__global__ __launch_bounds__(256) void rnorm_kernel(const float* __restrict__ x,
                                                    float* __restrict__ rnorm) {
    int idx = blockIdx.x * 256 + threadIdx.x;      // over BZ*LDIM = 16384
    int b = idx >> 12;
    int l = idx & (LDIM - 1);
    const float* xb = x + (size_t)b * NC * LDIM + l;
    float s = 0.f;
#pragma unroll 8
    for (int c = 0; c < NC; ++c) {
        float v = xb[(size_t)c * LDIM] + EPSK;
        s += v * v;
    }
    rnorm[idx] = 1.0f / sqrtf(s);
}

// ---------------- kconv: Kcl[b][c][l] fp16 and Klc[b][l][c] fp16 ----------------
__global__ __launch_bounds__(256) void kconv_kernel(const float* __restrict__ x,
                                                    const float* __restrict__ rn,
                                                    _Float16* __restrict__ Kcl,
                                                    _Float16* __restrict__ Klc) {
    __shared__ _Float16 t[64][72];
    int b = blockIdx.z, c0 = blockIdx.y * 64, l0 = blockIdx.x * 64;
    int tid = threadIdx.x;
    int r = tid >> 2, q = (tid & 3) * 16;
    const float* xr = x + ((size_t)(b * NC + c0 + r)) * LDIM + l0 + q;
    const float* rr = rn + b * LDIM + l0 + q;
    _Float16 h[16];
#pragma unroll
    for (int j = 0; j < 16; ++j)
        h[j] = (_Float16)((xr[j] + EPSK) * rr[j]);
    _Float16* kc = Kcl + ((size_t)(b * NC + c0 + r)) * LDIM + l0 + q;
    *(v8h*)kc = *(v8h*)h;
    *(v8h*)(kc + 8) = *(v8h*)(h + 8);
#pragma unroll
    for (int j = 0; j < 16; ++j) t[r][q + j] = h[j];
    __syncthreads();
    _Float16 g[16];
#pragma unroll
    for (int j = 0; j < 16; ++j) g[j] = t[q + j][r];
    _Float16* kl = Klc + ((size_t)(b * LDIM + l0 + r)) * NC + c0 + q;
    *(v8h*)kl = *(v8h*)g;
    *(v8h*)(kl + 8) = *(v8h*)(g + 8);
}

// ---------------- pool: PoolF[b][c][p] fp32, 3x3 clipped sum ----------------
__global__ __launch_bounds__(256) void pool_kernel(const float* __restrict__ x,
                                                   float* __restrict__ Pm) {
    size_t idx = (size_t)blockIdx.x * 256 + threadIdx.x;  // over BZ*NC*P66
    int p = (int)(idx % P66);
    size_t bc = idx / P66;
    int u = p / W66, v = p % W66;
    const float* xbc = x + bc * (size_t)LDIM;
    int i0 = max(u - 2, 0), i1 = min(u, 63);
    int j0 = max(v - 2, 0), j1 = min(v, 63);
    float s = 0.f;
    for (int i = i0; i <= i1; ++i)
        for (int j = j0; j <= j1; ++j)
            s += xbc[i * 64 + j];
    Pm[idx] = s;
}

// ---------------- ptrans: Pm16[b][p][c] fp16 = transpose(PoolF) ----------------
__global__ __launch_bounds__(256) void ptrans_kernel(const float* __restrict__ PoolF,
                                                     _Float16* __restrict__ Pm16) {
    __shared__ float t[64][65];
    int b = blockIdx.z, c0 = blockIdx.y * 64, p0 = blockIdx.x * 64;
    int tid = threadIdx.x;
    int r = tid >> 2, q = (tid & 3) * 16;
    const float* src = PoolF + ((size_t)(b * NC + c0 + r)) * P66 + p0 + q;
#pragma unroll
    for (int j = 0; j < 16; ++j) t[r][q + j] = src[j];  // overread lands in next ws region (safe)
    __syncthreads();
    if (p0 + r < P66) {
        _Float16 g[16];
#pragma unroll
        for (int j = 0; j < 16; ++j) g[j] = (_Float16)t[q + j][r];
        _Float16* dst = Pm16 + ((size_t)(b * P66 + p0 + r)) * NC + c0 + q;
        *(v8h*)dst = *(v8h*)g;
        *(v8h*)(dst + 8) = *(v8h*)(g + 8);
    }
}

// ---------------- GEMM1 (MFMA fp16): S[p][l] = sum_c Pm16[p][c]*Klc[l][c] ----------------
__global__ __launch_bounds__(256) void gemm1_mfma(const _Float16* __restrict__ Pm16,
                                                  const _Float16* __restrict__ Klc,
                                                  float* __restrict__ S) {
    __shared__ _Float16 As[128 * 32];
    __shared__ _Float16 Bs[128 * 32];
    int b = blockIdx.z;
    int p0 = blockIdx.y * 128;
    int l0 = blockIdx.x * 128;
    const _Float16* A = Pm16 + (size_t)b * P66 * NC;
    const _Float16* B = Klc + (size_t)b * LDIM * NC;
    float* C = S + (size_t)b * P66 * LDIM;
    int tid = threadIdx.x;
    int lane = tid & 63, wave = tid >> 6;
    int wm = (wave >> 1) * 64, wn = (wave & 1) * 64;
    int quad = lane >> 4, hn = lane & 15;
    int sr = tid >> 2, sk = (tid & 3) * 8;
    int pa0 = p0 + sr;      if (pa0 > P66 - 1) pa0 = P66 - 1;
    int pa1 = p0 + sr + 64; if (pa1 > P66 - 1) pa1 = P66 - 1;
    const _Float16* Ag0 = A + (size_t)pa0 * NC + sk;
    const _Float16* Ag1 = A + (size_t)pa1 * NC + sk;
    const _Float16* Bg0 = B + (size_t)(l0 + sr) * NC + sk;
    const _Float16* Bg1 = B + (size_t)(l0 + sr + 64) * NC + sk;
    char* lA = (char*)As + tid * 16;
    char* lB = (char*)Bs + tid * 16;
    v4f acc[4][4];
    v4f vz = {0.f, 0.f, 0.f, 0.f};
#pragma unroll
    for (int i = 0; i < 4; ++i)
#pragma unroll
        for (int j = 0; j < 4; ++j) acc[i][j] = vz;

    for (int k0 = 0; k0 < NC; k0 += 32) {
        __syncthreads();
        cp16(Ag0 + k0, lA);
        cp16(Ag1 + k0, lA + 4096);
        cp16(Bg0 + k0, lB);
        cp16(Bg1 + k0, lB + 4096);
        __syncthreads();
        v8h af[4], bfr[4];
#pragma unroll
        for (int t = 0; t < 4; ++t)
            af[t] = *(const v8h*)(As + (wm + t * 16 + hn) * 32 + quad * 8);
#pragma unroll
        for (int t = 0; t < 4; ++t)
            bfr[t] = *(const v8h*)(Bs + (wn + t * 16 + hn) * 32 + quad * 8);
#pragma unroll
        for (int i = 0; i < 4; ++i)
#pragma unroll
            for (int j = 0; j < 4; ++j)
                acc[i][j] = __builtin_amdgcn_mfma_f32_16x16x32_f16(af[i], bfr[j], acc[i][j], 0, 0, 0);
    }
#pragma unroll
    for (int i = 0; i < 4; ++i) {
        int pr = p0 + wm + i * 16 + quad * 4;
#pragma unroll
        for (int j = 0; j < 4; ++j) {
            int lc = l0 + wn + j * 16 + hn;
            float* Cp = C + (size_t)pr * LDIM + lc;
#pragma unroll
            for (int r = 0; r < 4; ++r)
                if (pr + r < P66) Cp[(size_t)r * LDIM] = acc[i][j][r];
        }
    }
}

// ---------------- softmax over l, in place on att rows ----------------
__global__ __launch_bounds__(256) void softmax_kernel(float* __restrict__ att) {
    float* row = att + (size_t)blockIdx.x * LDIM;
    int tid = threadIdx.x;
    float4 v[4];
    float mx = -1e30f;
#pragma unroll
    for (int i = 0; i < 4; ++i) {
        v[i] = ((float4*)row)[tid + i * 256];
        mx = fmaxf(mx, fmaxf(fmaxf(v[i].x, v[i].y), fmaxf(v[i].z, v[i].w)));
    }
    __shared__ float sred[4];
    __shared__ float ssum[4];
#pragma unroll
    for (int off = 32; off > 0; off >>= 1) mx = fmaxf(mx, __shfl_xor(mx, off));
    if ((tid & 63) == 0) sred[tid >> 6] = mx;
    __syncthreads();
    float m4 = fmaxf(fmaxf(sred[0], sred[1]), fmaxf(sred[2], sred[3]));
    float sum = 0.f;
#pragma unroll
    for (int i = 0; i < 4; ++i) {
        v[i].x = __expf(v[i].x - m4);
        v[i].y = __expf(v[i].y - m4);
        v[i].z = __expf(v[i].z - m4);
        v[i].w = __expf(v[i].w - m4);
        sum += (v[i].x + v[i].y) + (v[i].z + v[i].w);
    }
#pragma unroll
    for (int off = 32; off > 0; off >>= 1) sum += __shfl_xor(sum, off);
    if ((tid & 63) == 0) ssum[tid >> 6] = sum;
    __syncthreads();
    float r = 1.0f / (ssum[0] + ssum[1] + ssum[2] + ssum[3]);
#pragma unroll
    for (int i = 0; i < 4; ++i) {
        v[i].x *= r; v[i].y *= r; v[i].z *= r; v[i].w *= r;
        ((float4*)row)[tid + i * 256] = v[i];
    }
}

// ---------------- GEMM2 (MFMA fp16): out[c][i] = sum_l Kcl[c][l]*att[p(i)][l] ----------------
__global__ __launch_bounds__(256) void gemm2_mfma(const _Float16* __restrict__ Kcl,
                                                  const float* __restrict__ attF,
                                                  float* __restrict__ outp) {
    __shared__ _Float16 As[128 * 32];
    __shared__ float BsF[128 * 32];
    int b = blockIdx.z;
    int c0 = blockIdx.y * 128;
    int i0 = blockIdx.x * 128;
    const _Float16* A = Kcl + (size_t)b * NC * LDIM;
    const float* Batt = attF + (size_t)b * P66 * LDIM;
    float* C = outp + (size_t)b * NC * LDIM;
    int tid = threadIdx.x;
    int lane = tid & 63, wave = tid >> 6;
    int wm = (wave >> 1) * 64, wn = (wave & 1) * 64;
    int quad = lane >> 4, hn = lane & 15;
    int sr = tid >> 2, sk = (tid & 3) * 8;
    const _Float16* Ag0 = A + (size_t)(c0 + sr) * LDIM + sk;
    const _Float16* Ag1 = A + (size_t)(c0 + sr + 64) * LDIM + sk;
    int br = tid >> 3, bo = (tid & 7) * 4;
    const float* Bg[4];
#pragma unroll
    for (int ch = 0; ch < 4; ++ch) {
        int ii = i0 + ch * 32 + br;
        int p = ((ii >> 6) + 1) * W66 + (ii & 63) + 1;
        Bg[ch] = Batt + (size_t)p * LDIM + bo;
    }
    char* lA = (char*)As + tid * 16;
    char* lB = (char*)BsF + tid * 16;
    v4f acc[4][4];
    v4f vz = {0.f, 0.f, 0.f, 0.f};
#pragma unroll
    for (int i = 0; i < 4; ++i)
#pragma unroll
        for (int j = 0; j < 4; ++j) acc[i][j] = vz;

    for (int k0 = 0; k0 < LDIM; k0 += 32) {
        __syncthreads();
        cp16(Ag0 + k0, lA);
        cp16(Ag1 + k0, lA + 4096);
#pragma unroll
        for (int ch = 0; ch < 4; ++ch)
            cp16(Bg[ch] + k0, lB + ch * 4096);
        __syncthreads();
        v8h af[4], bfr[4];
#pragma unroll
        for (int t = 0; t < 4; ++t)
            af[t] = *(const v8h*)(As + (wm + t * 16 + hn) * 32 + quad * 8);
#pragma unroll
        for (int t = 0; t < 4; ++t) {
            const float* bp = BsF + (wn + t * 16 + hn) * 32 + quad * 8;
            v4f x0 = *(const v4f*)bp;
            v4f x1 = *(const v4f*)(bp + 4);
            v8h h;
#pragma unroll
            for (int j = 0; j < 4; ++j) { h[j] = (_Float16)x0[j]; h[j + 4] = (_Float16)x1[j]; }
            bfr[t] = h;
        }
#pragma unroll
        for (int i = 0; i < 4; ++i)
#pragma unroll
            for (int j = 0; j < 4; ++j)
                acc[i][j] = __builtin_amdgcn_mfma_f32_16x16x32_f16(af[i], bfr[j], acc[i][j], 0, 0, 0);
    }
#pragma unroll
    for (int i = 0; i < 4; ++i) {
        int cr = c0 + wm + i * 16 + quad * 4;
#pragma unroll
        for (int j = 0; j < 4; ++j) {
            int ic = i0 + wn + j * 16 + hn;
            float* Cp = C + (size_t)cr * LDIM + ic;
#pragma unroll
            for (int r = 0; r < 4; ++r)
                Cp[(size_t)r * LDIM] = acc[i][j][r];
        }
    }
}

extern "C" void kernel_launch(void* const* d_in, const int* in_sizes, int n_in,
                              void* d_out, int out_size, void* d_ws, size_t ws_size,
                              hipStream_t stream) {
    const float* x = (const float*)d_in[0];       // [4,256,64,64]
    float* out = (float*)d_out;                   // [4,256,64,64]
    float* att = (float*)d_out + 4194304;         // [4][4356][4096] position-major
    float* rn = (float*)d_ws;                     // 16384 f32
    _Float16* Kcl = (_Float16*)(rn + 16384);      // [4][256][4096] fp16
    _Float16* Klc = Kcl + (size_t)BZ * NC * LDIM; // [4][4096][256] fp16
    float* PoolF = (float*)(Klc + (size_t)BZ * NC * LDIM);  // [4][256][4356] f32
    _Float16* Pm16 = (_Float16*)(PoolF + (size_t)BZ * NC * P66);  // [4][4356][256] fp16

    rnorm_kernel<<<64, 256, 0, stream>>>(x, rn);
    kconv_kernel<<<dim3(64, 4, BZ), 256, 0, stream>>>(x, rn, Kcl, Klc);
    pool_kernel<<<17424, 256, 0, stream>>>(x, PoolF);
    ptrans_kernel<<<dim3(69, 4, BZ), 256, 0, stream>>>(PoolF, Pm16);
    gemm1_mfma<<<dim3(32, 35, BZ), 256, 0, stream>>>(Pm16, Klc, att);
    softmax_kernel<<<17424, 256, 0, stream>>>(att);
    gemm2_mfma<<<dim3(32, 2, BZ), 256, 0, stream>>>(Kcl, att, out);
}